// Round 2
// baseline (32001.526 us; speedup 1.0000x reference)
//
#include <hip/hip_runtime.h>
#include <hip/hip_bf16.h>

// ---------------------------------------------------------------------------
// 2-layer LSTM decoder, B=64, T=25, H=2048, IN=OUT=66, hardtanh feedback.
// v2: weights/activations pre-permuted into MFMA-fragment order so every
// step-time load is a coalesced 1KB wave load. Block = 8 units x 4 gates x
// 64 batches; 8 waves = 8 K-slices; 8 accs/wave; LDS K-reduction + fused cell.
// ---------------------------------------------------------------------------

typedef short bfrag  __attribute__((ext_vector_type(8)));   // 8 bf16 (4 VGPR)
typedef float accv   __attribute__((ext_vector_type(4)));   // 4 fp32 acc
typedef float vfloat4 __attribute__((ext_vector_type(4)));
typedef unsigned short usvec8 __attribute__((ext_vector_type(8)));

#define LD8(p) (*(const bfrag*)(p))

__device__ __forceinline__ unsigned short f2bf(float x) {
    unsigned int u = __float_as_uint(x);
    unsigned int r = u + 0x7FFFu + ((u >> 16) & 1u);   // RTNE
    return (unsigned short)(r >> 16);
}
__device__ __forceinline__ float bf2f(unsigned short u) {
    return __uint_as_float(((unsigned int)u) << 16);
}

// Activation fragment layout ("Ap", KC chunks):  element (b, k) lives at
//   [( (b>>4)*KC + (k>>5) )*512 + ( ((k>>3)&3)*16 + (b&15) )*8 + (k&7)]
__device__ __forceinline__ int ap_idx(int b, int j, int KC) {
    return (((b >> 4) * KC + (j >> 5)) << 9) + ((((j >> 3) & 3) * 16 + (b & 15)) << 3) + (j & 7);
}

// Weight fragment layout ("Bp"): n-tile (jb,p) holds rows
//   row = (2p + (n>>3))*2048 + jb*8 + (n&7),  n = lane&15
//   element at [ ((jb*2+p)*KC + kc)*512 + lane*8 + j ],  k = kc*32 + (lane>>4)*8 + j

// --------------------------- weight cast+permute (big) ---------------------
// Whh0 / Wih1 / Whh1: each [8192][2048] fp32 -> bf16 fragment order.
__global__ __launch_bounds__(256) void cast_big(
        const float* __restrict__ s0, const float* __restrict__ s1, const float* __restrict__ s2,
        unsigned short* __restrict__ d0, unsigned short* __restrict__ d1, unsigned short* __restrict__ d2) {
    unsigned int tid = blockIdx.x * 256 + threadIdx.x;   // 0 .. 6291455
    unsigned int a = tid >> 21;                          // 2097152 frags per matrix
    unsigned int r = tid & 2097151u;
    const float* src = (a == 0) ? s0 : (a == 1) ? s1 : s2;
    unsigned short* dst = (a == 0) ? d0 : (a == 1) ? d1 : d2;
    unsigned int lane = r & 63u;
    unsigned int kc   = (r >> 6) & 63u;
    unsigned int p    = (r >> 12) & 1u;
    unsigned int jb   = r >> 13;
    unsigned int n = lane & 15u, quad = lane >> 4;
    unsigned int row = (2u * p + (n >> 3)) * 2048u + jb * 8u + (n & 7u);
    unsigned int k0  = kc * 32u + quad * 8u;
    const float* sp = src + (size_t)row * 2048 + k0;
    vfloat4 v0 = *(const vfloat4*)sp;
    vfloat4 v1 = *(const vfloat4*)(sp + 4);
    usvec8 u = { f2bf(v0.x), f2bf(v0.y), f2bf(v0.z), f2bf(v0.w),
                 f2bf(v1.x), f2bf(v1.y), f2bf(v1.z), f2bf(v1.w) };
    *(usvec8*)(dst + (size_t)r * 8) = u;
}

// --------------------------- state init ------------------------------------
__global__ __launch_bounds__(256) void init_state(
        const float* __restrict__ inputs, const float* __restrict__ hiddens,
        const float* __restrict__ cells,  const float* __restrict__ wih0,
        unsigned short* __restrict__ wih0p,
        unsigned short* __restrict__ h0, unsigned short* __restrict__ h1,
        float* __restrict__ c0, float* __restrict__ c1,
        unsigned short* __restrict__ xb,
        float* __restrict__ bsum0, float* __restrict__ bsum1,
        const float* __restrict__ bih0, const float* __restrict__ bhh0,
        const float* __restrict__ bih1, const float* __restrict__ bhh1) {
    int i = blockIdx.x * 256 + threadIdx.x;
    if (i < 786432) {                        // Wih0 pad-permute: [8192][66] -> Bp KC=3
        int jo = i & 7, lane = (i >> 3) & 63;
        int t2 = i >> 9, kc = t2 % 3, t3 = t2 / 3, p = t3 & 1, jb = t3 >> 1;
        int n = lane & 15, quad = lane >> 4;
        int row = (2 * p + (n >> 3)) * 2048 + jb * 8 + (n & 7);
        int k = kc * 32 + quad * 8 + jo;
        wih0p[i] = (k < 66) ? f2bf(wih0[row * 66 + k]) : (unsigned short)0;
        return;
    }
    i -= 786432;
    if (i < 131072) { int b = i >> 11, j = i & 2047; h0[ap_idx(b, j, 64)] = f2bf(hiddens[i]); return; }
    i -= 131072;
    if (i < 131072) { int b = i >> 11, j = i & 2047; h1[ap_idx(b, j, 64)] = f2bf(hiddens[131072 + i]); return; }
    i -= 131072;
    if (i < 131072) { int b = i >> 11, j = i & 2047; c0[(j >> 3) * 512 + b * 8 + (j & 7)] = cells[i]; return; }
    i -= 131072;
    if (i < 131072) { int b = i >> 11, j = i & 2047; c1[(j >> 3) * 512 + b * 8 + (j & 7)] = cells[131072 + i]; return; }
    i -= 131072;
    if (i < 6144) {                          // x pad-permute -> Ap KC=3
        int jo = i & 7, lane = (i >> 3) & 63;
        int t2 = i >> 9, kc = t2 % 3, m = t2 / 3;
        int b = m * 16 + (lane & 15);
        int k = kc * 32 + (lane >> 4) * 8 + jo;
        xb[i] = (k < 66) ? f2bf(inputs[b * 66 + k]) : (unsigned short)0;
        return;
    }
    i -= 6144;
    if (i < 8192) { bsum0[i] = bih0[i] + bhh0[i]; return; }
    i -= 8192;
    if (i < 8192) { bsum1[i] = bih1[i] + bhh1[i]; }
}

// --------------------------- fused LSTM layer v2 ---------------------------
// grid 256 blocks x 512 threads. Block jb: units jb*8..jb*8+7, all gates, all
// batches. Wave w = K-slice (chunks c = w, w+8, ...). 8 accs/wave:
// acc[mi][p] = (m-tile mi) x (n-tile p). LDS reduction over 8 slices + cell.
__global__ __launch_bounds__(512) void lstm2(
        const unsigned short* __restrict__ Ap1, const unsigned short* __restrict__ Bp1, int KC1,
        const unsigned short* __restrict__ Ap2, const unsigned short* __restrict__ Bp2, int KC2,
        const float* __restrict__ bsum,
        float* __restrict__ c_state,             // [jb*512 + tid] fp32
        unsigned short* __restrict__ h_out) {    // Ap layout, KC=64
    __shared__ float gsm[8][64][32];             // 64 KB, XOR-swizzled cols
    int tid = threadIdx.x, lane = tid & 63, w = tid >> 6;
    int jb = blockIdx.x;
    int KT = KC1 + KC2;
    int nc = (KT - w + 7) >> 3;                  // chunks for this wave

    accv acc[4][2] = {};
    bfrag fa[2][4], fb[2][2];

    auto load = [&](int cc, bfrag* A4, bfrag* B2) {
        const unsigned short *Ab, *Bb; int KC, kc;
        if (cc < KC1) { Ab = Ap1; Bb = Bp1; KC = KC1; kc = cc; }
        else          { Ab = Ap2; Bb = Bp2; KC = KC2; kc = cc - KC1; }
        size_t astride = (size_t)KC << 9;
        const unsigned short* ap = Ab + ((size_t)kc << 9) + lane * 8;
        A4[0] = LD8(ap);
        A4[1] = LD8(ap + astride);
        A4[2] = LD8(ap + 2 * astride);
        A4[3] = LD8(ap + 3 * astride);
        const unsigned short* bp = Bb + (((size_t)(jb * 2) * KC + kc) << 9) + lane * 8;
        B2[0] = LD8(bp);
        B2[1] = LD8(bp + astride);
    };

    if (nc > 0) load(w, fa[0], fb[0]);
    if (nc > 1) load(w + 8, fa[1], fb[1]);
    for (int i = 0; i < nc; ++i) {
        bfrag* A4 = fa[i & 1];
        bfrag* B2 = fb[i & 1];
        #pragma unroll
        for (int mi = 0; mi < 4; ++mi)
            #pragma unroll
            for (int p = 0; p < 2; ++p)
                acc[mi][p] = __builtin_amdgcn_mfma_f32_16x16x32_bf16(A4[mi], B2[p], acc[mi][p], 0, 0, 0);
        if (i + 2 < nc) load(w + 8 * (i + 2), fa[i & 1], fb[i & 1]);
    }

    int n = lane & 15, quad = lane >> 4;
    #pragma unroll
    for (int mi = 0; mi < 4; ++mi)
        #pragma unroll
        for (int p = 0; p < 2; ++p)
            #pragma unroll
            for (int r = 0; r < 4; ++r) {
                int R = mi * 16 + quad * 4 + r;          // batch
                int C = p * 16 + n;                      // gate*8 + unit
                gsm[w][R][C ^ ((R & 3) << 3)] = acc[mi][p][r];
            }
    __syncthreads();

    int b = tid >> 3, jj = tid & 7;
    float g4[4];
    #pragma unroll
    for (int g = 0; g < 4; ++g) {
        int Cp = (g * 8 + jj) ^ ((b & 3) << 3);
        float s = 0.f;
        #pragma unroll
        for (int w8 = 0; w8 < 8; ++w8) s += gsm[w8][b][Cp];
        g4[g] = s;
    }
    int j = jb * 8 + jj;
    float gi = g4[0] + bsum[j];
    float gf = g4[1] + bsum[2048 + j];
    float gg = g4[2] + bsum[4096 + j];
    float go = g4[3] + bsum[6144 + j];
    float iv = 1.f / (1.f + __expf(-gi));
    float fv = 1.f / (1.f + __expf(-gf));
    float gv = tanhf(gg);
    float ov = 1.f / (1.f + __expf(-go));
    float cp = c_state[jb * 512 + tid];
    float cn = fv * cp + iv * gv;
    float hn = ov * tanhf(cn);
    c_state[jb * 512 + tid] = cn;
    h_out[ap_idx(b, j, 64)] = f2bf(hn);
}

// --------------------------- FC + hardtanh + feedback ----------------------
__global__ __launch_bounds__(512) void fc2(
        const unsigned short* __restrict__ h1,   // Ap layout, KC=64, bf16
        const float* __restrict__ fcw,           // [66][2048]
        const float* __restrict__ fcb,           // [66]
        float* __restrict__ out,                 // [64][25][66]
        unsigned short* __restrict__ xb,         // Ap layout, KC=3
        int t) {
    __shared__ float red[8][64];
    int o = blockIdx.x;
    int b = threadIdx.x & 63, w = threadIdx.x >> 6;
    const float* wrow = fcw + (size_t)o * 2048;
    float acc = 0.f;
    for (int kc = w; kc < 64; kc += 8) {
        const unsigned short* hp = h1 + (((size_t)(b >> 4) * 64 + kc) << 9) + (b & 15) * 8;
        const float* wp = wrow + kc * 32;
        #pragma unroll
        for (int q = 0; q < 4; ++q) {
            usvec8 hv = *(const usvec8*)(hp + q * 128);
            vfloat4 w0 = *(const vfloat4*)(wp + q * 8);
            vfloat4 w1 = *(const vfloat4*)(wp + q * 8 + 4);
            acc = fmaf(bf2f(hv[0]), w0.x, acc);
            acc = fmaf(bf2f(hv[1]), w0.y, acc);
            acc = fmaf(bf2f(hv[2]), w0.z, acc);
            acc = fmaf(bf2f(hv[3]), w0.w, acc);
            acc = fmaf(bf2f(hv[4]), w1.x, acc);
            acc = fmaf(bf2f(hv[5]), w1.y, acc);
            acc = fmaf(bf2f(hv[6]), w1.z, acc);
            acc = fmaf(bf2f(hv[7]), w1.w, acc);
        }
    }
    red[w][b] = acc;
    __syncthreads();
    if (threadIdx.x < 64) {
        int bb = threadIdx.x;
        float v = fcb[o];
        #pragma unroll
        for (int q = 0; q < 8; ++q) v += red[q][bb];
        v = fminf(1.f, fmaxf(-1.f, v));
        out[((size_t)bb * 25 + t) * 66 + o] = v;
        int kc = o >> 5, q = (o >> 3) & 3, jo = o & 7;
        xb[(((bb >> 4) * 3 + kc) << 9) + (q * 16 + (bb & 15)) * 8 + jo] = f2bf(v);
    }
}

// ---------------------------------------------------------------------------
extern "C" void kernel_launch(void* const* d_in, const int* in_sizes, int n_in,
                              void* d_out, int out_size, void* d_ws, size_t ws_size,
                              hipStream_t stream) {
    (void)in_sizes; (void)n_in; (void)out_size; (void)ws_size;
    const float* inputs  = (const float*)d_in[0];
    const float* hiddens = (const float*)d_in[1];
    const float* cells   = (const float*)d_in[2];
    const float* W_ih0   = (const float*)d_in[3];
    const float* W_hh0   = (const float*)d_in[4];
    const float* b_ih0   = (const float*)d_in[5];
    const float* b_hh0   = (const float*)d_in[6];
    const float* W_ih1   = (const float*)d_in[7];
    const float* W_hh1   = (const float*)d_in[8];
    const float* b_ih1   = (const float*)d_in[9];
    const float* b_hh1   = (const float*)d_in[10];
    const float* fc_w    = (const float*)d_in[11];
    const float* fc_b    = (const float*)d_in[12];
    float* out = (float*)d_out;

    // workspace layout (~104.4 MB)
    unsigned short* whh0p = (unsigned short*)d_ws;     // 16777216 shorts
    unsigned short* wih1p = whh0p + 16777216;
    unsigned short* whh1p = wih1p + 16777216;
    unsigned short* wih0p = whh1p + 16777216;          // 786432 (Bp KC=3)
    unsigned short* h0a   = wih0p + 786432;            // 131072 each (Ap KC=64)
    unsigned short* h0b   = h0a + 131072;
    unsigned short* h1a   = h0b + 131072;
    unsigned short* h1b   = h1a + 131072;
    unsigned short* xb    = h1b + 131072;              // 6144 (Ap KC=3)
    float* c0    = (float*)(xb + 6144);                // 131072 fp32 each
    float* c1    = c0 + 131072;
    float* bsum0 = c1 + 131072;                        // 8192 fp32 each
    float* bsum1 = bsum0 + 8192;

    cast_big<<<24576, 256, 0, stream>>>(W_hh0, W_ih1, W_hh1, whh0p, wih1p, whh1p);
    init_state<<<5208, 256, 0, stream>>>(inputs, hiddens, cells, W_ih0,
                                         wih0p, h0a, h1a, c0, c1, xb,
                                         bsum0, bsum1, b_ih0, b_hh0, b_ih1, b_hh1);

    unsigned short* h0buf[2] = {h0a, h0b};
    unsigned short* h1buf[2] = {h1a, h1b};
    for (int t = 0; t < 25; ++t) {
        int cur = t & 1, nxt = cur ^ 1;
        lstm2<<<256, 512, 0, stream>>>(xb, wih0p, 3,
                                       h0buf[cur], whh0p, 64,
                                       bsum0, c0, h0buf[nxt]);
        lstm2<<<256, 512, 0, stream>>>(h0buf[nxt], wih1p, 64,
                                       h1buf[cur], whh1p, 64,
                                       bsum1, c1, h1buf[nxt]);
        fc2<<<66, 512, 0, stream>>>(h1buf[nxt], fc_w, fc_b, out, xb, t);
    }
}

// Round 3
// 978.629 us; speedup vs baseline: 32.7004x; 32.7004x over previous
//
#include <hip/hip_runtime.h>
#include <hip/hip_bf16.h>

// ---------------------------------------------------------------------------
// 2-layer LSTM decoder, B=64, T=25, H=2048, IN=OUT=66, hardtanh feedback.
// v3: v2's fragment-order layouts kept; K-loop made fully static
// (compile-time trip counts, full unroll, static register buffer rotation)
// so MFMA operands stay in VGPRs instead of scratch.
// ---------------------------------------------------------------------------

typedef short bfrag  __attribute__((ext_vector_type(8)));   // 8 bf16 (4 VGPR)
typedef float accv   __attribute__((ext_vector_type(4)));   // 4 fp32 acc
typedef float vfloat4 __attribute__((ext_vector_type(4)));
typedef unsigned short usvec8 __attribute__((ext_vector_type(8)));

#define LD8(p) (*(const bfrag*)(p))

__device__ __forceinline__ unsigned short f2bf(float x) {
    unsigned int u = __float_as_uint(x);
    unsigned int r = u + 0x7FFFu + ((u >> 16) & 1u);   // RTNE
    return (unsigned short)(r >> 16);
}
__device__ __forceinline__ float bf2f(unsigned short u) {
    return __uint_as_float(((unsigned int)u) << 16);
}

// Activation fragment layout ("Ap", KC chunks of 32 k-elements):
//   (b, k) -> [((b>>4)*KC + (k>>5))*512 + (((k>>3)&3)*16 + (b&15))*8 + (k&7)]
__device__ __forceinline__ int ap_idx(int b, int j, int KC) {
    return (((b >> 4) * KC + (j >> 5)) << 9) + ((((j >> 3) & 3) * 16 + (b & 15)) << 3) + (j & 7);
}

// Weight fragment layout ("Bp"): n-tile (jb,p) holds rows
//   row = (2p + (n>>3))*2048 + jb*8 + (n&7),  n = lane&15
//   element at [((jb*2+p)*KC + kc)*512 + lane*8 + j],  k = kc*32 + (lane>>4)*8 + j

// --------------------------- weight cast+permute (big) ---------------------
__global__ __launch_bounds__(256) void cast_big(
        const float* __restrict__ s0, const float* __restrict__ s1, const float* __restrict__ s2,
        unsigned short* __restrict__ d0, unsigned short* __restrict__ d1, unsigned short* __restrict__ d2) {
    unsigned int tid = blockIdx.x * 256 + threadIdx.x;   // 0 .. 6291455
    unsigned int a = tid >> 21;                          // 2097152 frags per matrix
    unsigned int r = tid & 2097151u;
    const float* src = (a == 0) ? s0 : (a == 1) ? s1 : s2;
    unsigned short* dst = (a == 0) ? d0 : (a == 1) ? d1 : d2;
    unsigned int lane = r & 63u;
    unsigned int kc   = (r >> 6) & 63u;
    unsigned int p    = (r >> 12) & 1u;
    unsigned int jb   = r >> 13;
    unsigned int n = lane & 15u, quad = lane >> 4;
    unsigned int row = (2u * p + (n >> 3)) * 2048u + jb * 8u + (n & 7u);
    unsigned int k0  = kc * 32u + quad * 8u;
    const float* sp = src + (size_t)row * 2048 + k0;
    vfloat4 v0 = *(const vfloat4*)sp;
    vfloat4 v1 = *(const vfloat4*)(sp + 4);
    usvec8 u = { f2bf(v0.x), f2bf(v0.y), f2bf(v0.z), f2bf(v0.w),
                 f2bf(v1.x), f2bf(v1.y), f2bf(v1.z), f2bf(v1.w) };
    *(usvec8*)(dst + (size_t)r * 8) = u;
}

// --------------------------- state init ------------------------------------
__global__ __launch_bounds__(256) void init_state(
        const float* __restrict__ inputs, const float* __restrict__ hiddens,
        const float* __restrict__ cells,  const float* __restrict__ wih0,
        unsigned short* __restrict__ wih0p,
        unsigned short* __restrict__ h0, unsigned short* __restrict__ h1,
        float* __restrict__ c0, float* __restrict__ c1,
        unsigned short* __restrict__ xb,
        float* __restrict__ bsum0, float* __restrict__ bsum1,
        const float* __restrict__ bih0, const float* __restrict__ bhh0,
        const float* __restrict__ bih1, const float* __restrict__ bhh1) {
    int i = blockIdx.x * 256 + threadIdx.x;
    if (i < 786432) {                        // Wih0 pad-permute: [8192][66] -> Bp KC=3
        int jo = i & 7, lane = (i >> 3) & 63;
        int t2 = i >> 9, kc = t2 % 3, t3 = t2 / 3, p = t3 & 1, jb = t3 >> 1;
        int n = lane & 15, quad = lane >> 4;
        int row = (2 * p + (n >> 3)) * 2048 + jb * 8 + (n & 7);
        int k = kc * 32 + quad * 8 + jo;
        wih0p[i] = (k < 66) ? f2bf(wih0[row * 66 + k]) : (unsigned short)0;
        return;
    }
    i -= 786432;
    if (i < 131072) { int b = i >> 11, j = i & 2047; h0[ap_idx(b, j, 64)] = f2bf(hiddens[i]); return; }
    i -= 131072;
    if (i < 131072) { int b = i >> 11, j = i & 2047; h1[ap_idx(b, j, 64)] = f2bf(hiddens[131072 + i]); return; }
    i -= 131072;
    if (i < 131072) { int b = i >> 11, j = i & 2047; c0[(j >> 3) * 512 + b * 8 + (j & 7)] = cells[i]; return; }
    i -= 131072;
    if (i < 131072) { int b = i >> 11, j = i & 2047; c1[(j >> 3) * 512 + b * 8 + (j & 7)] = cells[131072 + i]; return; }
    i -= 131072;
    if (i < 16384) {                         // x pad-permute -> Ap KC=8 (k padded to 256)
        int jo = i & 7, lane = (i >> 3) & 63;
        int t2 = i >> 9;                     // 0..31
        int kc = t2 & 7, m = t2 >> 3;
        int b = m * 16 + (lane & 15);
        int k = kc * 32 + (lane >> 4) * 8 + jo;
        xb[i] = (k < 66) ? f2bf(inputs[b * 66 + k]) : (unsigned short)0;
        return;
    }
    i -= 16384;
    if (i < 8192) { bsum0[i] = bih0[i] + bhh0[i]; return; }
    i -= 8192;
    if (i < 8192) { bsum1[i] = bih1[i] + bhh1[i]; }
}

// --------------------------- fused LSTM layer v3 ---------------------------
// grid 256 x 512. Block jb: units jb*8..+7, all 4 gates, all 64 batches.
// Wave w = K-slice: chunks c = w + 8*i, fully static schedule.
// L0: source1 = (x KC=8 padded, Wih0 KC=3) -> 1 chunk (A-zeros make B
//     don't-care for w>=3, so B kc is clamped); source2 = (h0, Whh0), 8 chunks.
// L1: source1 = (h0new, Wih1), 8 chunks; source2 = (h1prev, Whh1), 8 chunks.
template<bool L0>
__global__ __launch_bounds__(512, 4) void lstm3(
        const unsigned short* __restrict__ Ap1, const unsigned short* __restrict__ Bp1,
        const unsigned short* __restrict__ Ap2, const unsigned short* __restrict__ Bp2,
        const float* __restrict__ bsum,
        float* __restrict__ c_state,             // [jb*512 + tid] fp32
        unsigned short* __restrict__ h_out) {    // Ap layout, KC=64
    __shared__ float gsm[8][64][32];             // 64 KB, XOR-swizzled cols
    int tid = threadIdx.x, lane = tid & 63, w = tid >> 6;
    int jb = blockIdx.x;
    constexpr int N1  = L0 ? 1 : 8;
    constexpr int N2  = 8;
    constexpr int NC  = N1 + N2;
    constexpr int KA1 = L0 ? 8 : 64;             // A1 layout KC
    constexpr int KB1 = L0 ? 3 : 64;             // B1 layout KC
    constexpr int KC2 = 64;
    constexpr int PF  = 2;

    int kB1 = L0 ? (w < 3 ? w : 0) : w;          // clamp: A is zero when w>=3
    const unsigned short* a1 = Ap1 + ((size_t)w << 9) + lane * 8;
    const unsigned short* b1 = Bp1 + (((size_t)(2 * jb) * KB1 + kB1) << 9) + lane * 8;
    const unsigned short* a2 = Ap2 + ((size_t)w << 9) + lane * 8;
    const unsigned short* b2 = Bp2 + (((size_t)(2 * jb) * KC2 + w) << 9) + lane * 8;

    accv acc[4][2] = {};
    bfrag fA[PF][4], fB[PF][2];

    auto issue = [&](int i) {                    // i is a constant after unroll
        int s = i % PF;
        const unsigned short *ap, *bp;
        int sa, sb;
        if (i < N1) { ap = a1 + ((size_t)i << 12); bp = b1 + ((size_t)i << 12); sa = KA1 << 9; sb = KB1 << 9; }
        else { int ii = i - N1; ap = a2 + ((size_t)ii << 12); bp = b2 + ((size_t)ii << 12); sa = KC2 << 9; sb = KC2 << 9; }
        fA[s][0] = LD8(ap);
        fA[s][1] = LD8(ap + sa);
        fA[s][2] = LD8(ap + 2 * sa);
        fA[s][3] = LD8(ap + 3 * sa);
        fB[s][0] = LD8(bp);
        fB[s][1] = LD8(bp + sb);
    };

    #pragma unroll
    for (int i = 0; i < PF; ++i) issue(i);
    #pragma unroll
    for (int i = 0; i < NC; ++i) {
        int s = i % PF;
        #pragma unroll
        for (int mi = 0; mi < 4; ++mi)
            #pragma unroll
            for (int p = 0; p < 2; ++p)
                acc[mi][p] = __builtin_amdgcn_mfma_f32_16x16x32_bf16(fA[s][mi], fB[s][p], acc[mi][p], 0, 0, 0);
        if (i + PF < NC) issue(i + PF);
    }

    int n = lane & 15, quad = lane >> 4;
    #pragma unroll
    for (int mi = 0; mi < 4; ++mi)
        #pragma unroll
        for (int p = 0; p < 2; ++p)
            #pragma unroll
            for (int r = 0; r < 4; ++r) {
                int R = mi * 16 + quad * 4 + r;          // batch
                int C = p * 16 + n;                      // gate*8 + unit
                gsm[w][R][C ^ ((R & 3) << 3)] = acc[mi][p][r];
            }
    __syncthreads();

    int b = tid >> 3, jj = tid & 7;
    float g4[4];
    #pragma unroll
    for (int g = 0; g < 4; ++g) {
        int Cp = (g * 8 + jj) ^ ((b & 3) << 3);
        float s = 0.f;
        #pragma unroll
        for (int w8 = 0; w8 < 8; ++w8) s += gsm[w8][b][Cp];
        g4[g] = s;
    }
    int j = jb * 8 + jj;
    float gi = g4[0] + bsum[j];
    float gf = g4[1] + bsum[2048 + j];
    float gg = g4[2] + bsum[4096 + j];
    float go = g4[3] + bsum[6144 + j];
    float iv = 1.f / (1.f + __expf(-gi));
    float fv = 1.f / (1.f + __expf(-gf));
    float gv = tanhf(gg);
    float ov = 1.f / (1.f + __expf(-go));
    float cp = c_state[jb * 512 + tid];
    float cn = fv * cp + iv * gv;
    float hn = ov * tanhf(cn);
    c_state[jb * 512 + tid] = cn;
    h_out[ap_idx(b, j, 64)] = f2bf(hn);
}

// --------------------------- FC + hardtanh + feedback ----------------------
__global__ __launch_bounds__(512) void fc2(
        const unsigned short* __restrict__ h1,   // Ap layout, KC=64, bf16
        const float* __restrict__ fcw,           // [66][2048]
        const float* __restrict__ fcb,           // [66]
        float* __restrict__ out,                 // [64][25][66]
        unsigned short* __restrict__ xb,         // Ap layout, KC=8
        int t) {
    __shared__ float red[8][64];
    int o = blockIdx.x;
    int b = threadIdx.x & 63, w = threadIdx.x >> 6;
    const float* wrow = fcw + (size_t)o * 2048;
    float acc = 0.f;
    for (int kc = w; kc < 64; kc += 8) {
        const unsigned short* hp = h1 + (((size_t)(b >> 4) * 64 + kc) << 9) + (b & 15) * 8;
        const float* wp = wrow + kc * 32;
        #pragma unroll
        for (int q = 0; q < 4; ++q) {
            usvec8 hv = *(const usvec8*)(hp + q * 128);
            vfloat4 w0 = *(const vfloat4*)(wp + q * 8);
            vfloat4 w1 = *(const vfloat4*)(wp + q * 8 + 4);
            acc = fmaf(bf2f(hv[0]), w0.x, acc);
            acc = fmaf(bf2f(hv[1]), w0.y, acc);
            acc = fmaf(bf2f(hv[2]), w0.z, acc);
            acc = fmaf(bf2f(hv[3]), w0.w, acc);
            acc = fmaf(bf2f(hv[4]), w1.x, acc);
            acc = fmaf(bf2f(hv[5]), w1.y, acc);
            acc = fmaf(bf2f(hv[6]), w1.z, acc);
            acc = fmaf(bf2f(hv[7]), w1.w, acc);
        }
    }
    red[w][b] = acc;
    __syncthreads();
    if (threadIdx.x < 64) {
        int bb = threadIdx.x;
        float v = fcb[o];
        #pragma unroll
        for (int q = 0; q < 8; ++q) v += red[q][bb];
        v = fminf(1.f, fmaxf(-1.f, v));
        out[((size_t)bb * 25 + t) * 66 + o] = v;
        int kc = o >> 5;                         // 0..2 (< 8 pad chunks)
        xb[(((size_t)(bb >> 4) * 8 + kc) << 9) + ((((o >> 3) & 3) * 16 + (bb & 15)) << 3) + (o & 7)] = f2bf(v);
    }
}

// ---------------------------------------------------------------------------
extern "C" void kernel_launch(void* const* d_in, const int* in_sizes, int n_in,
                              void* d_out, int out_size, void* d_ws, size_t ws_size,
                              hipStream_t stream) {
    (void)in_sizes; (void)n_in; (void)out_size; (void)ws_size;
    const float* inputs  = (const float*)d_in[0];
    const float* hiddens = (const float*)d_in[1];
    const float* cells   = (const float*)d_in[2];
    const float* W_ih0   = (const float*)d_in[3];
    const float* W_hh0   = (const float*)d_in[4];
    const float* b_ih0   = (const float*)d_in[5];
    const float* b_hh0   = (const float*)d_in[6];
    const float* W_ih1   = (const float*)d_in[7];
    const float* W_hh1   = (const float*)d_in[8];
    const float* b_ih1   = (const float*)d_in[9];
    const float* b_hh1   = (const float*)d_in[10];
    const float* fc_w    = (const float*)d_in[11];
    const float* fc_b    = (const float*)d_in[12];
    float* out = (float*)d_out;

    // workspace layout (~104.4 MB)
    unsigned short* whh0p = (unsigned short*)d_ws;     // 16777216 shorts each
    unsigned short* wih1p = whh0p + 16777216;
    unsigned short* whh1p = wih1p + 16777216;
    unsigned short* wih0p = whh1p + 16777216;          // 786432 (Bp KC=3)
    unsigned short* h0a   = wih0p + 786432;            // 131072 each (Ap KC=64)
    unsigned short* h0b   = h0a + 131072;
    unsigned short* h1a   = h0b + 131072;
    unsigned short* h1b   = h1a + 131072;
    unsigned short* xb    = h1b + 131072;              // 16384 (Ap KC=8, padded)
    float* c0    = (float*)(xb + 16384);               // 131072 fp32 each
    float* c1    = c0 + 131072;
    float* bsum0 = c1 + 131072;                        // 8192 fp32 each
    float* bsum1 = bsum0 + 8192;

    cast_big<<<24576, 256, 0, stream>>>(W_hh0, W_ih1, W_hh1, whh0p, wih1p, whh1p);
    init_state<<<5248, 256, 0, stream>>>(inputs, hiddens, cells, W_ih0,
                                         wih0p, h0a, h1a, c0, c1, xb,
                                         bsum0, bsum1, b_ih0, b_hh0, b_ih1, b_hh1);

    unsigned short* h0buf[2] = {h0a, h0b};
    unsigned short* h1buf[2] = {h1a, h1b};
    for (int t = 0; t < 25; ++t) {
        int cur = t & 1, nxt = cur ^ 1;
        lstm3<true><<<256, 512, 0, stream>>>(xb, wih0p,
                                             h0buf[cur], whh0p,
                                             bsum0, c0, h0buf[nxt]);
        lstm3<false><<<256, 512, 0, stream>>>(h0buf[nxt], wih1p,
                                              h1buf[cur], whh1p,
                                              bsum1, c1, h1buf[nxt]);
        fc2<<<66, 512, 0, stream>>>(h1buf[nxt], fc_w, fc_b, out, xb, t);
    }
}